// Round 9
// baseline (401.405 us; speedup 1.0000x reference)
//
#include <hip/hip_runtime.h>
#include <hip/hip_bf16.h>

#define BN 8
#define SS 1024
#define CC 512
#define HH 8
#define DD 64
#define PP 16
#define KT 1040

typedef __hip_bfloat16 bf16;
typedef __attribute__((ext_vector_type(8))) short short8;
typedef __attribute__((ext_vector_type(4))) float f32x4;
typedef __attribute__((ext_vector_type(2))) float f32x2;

__device__ __forceinline__ short f2s(float v){ bf16 b = __float2bfloat16(v); return *(short*)&b; }
__device__ __forceinline__ float s2f(short s){ bf16 b; *(short*)&b = s; return __bfloat162float(b); }

#define MFMA16(a,b,c) __builtin_amdgcn_mfma_f32_16x16x32_bf16(a,b,c,0,0,0)

// ---------------------------------------------------------------------------
// P0: weight pre-conversion to bf16 NT layouts.
// ---------------------------------------------------------------------------
__global__ __launch_bounds__(256) void prep_kernel(
    const float* __restrict__ fc_w, const float* __restrict__ c1w,
    const float* __restrict__ c2w, const float* __restrict__ Wq,
    const float* __restrict__ Wk, const float* __restrict__ Wv,
    short* __restrict__ Bfc, short* __restrict__ Bc1,
    short* __restrict__ Bc2, short* __restrict__ Bqkv)
{
    int i = blockIdx.x*256 + threadIdx.x;
    const int NFC = 512*512, NCV = 512*1536, NQ = 3*64*64;
    if (i < NFC) { Bfc[i] = f2s(fc_w[i]); return; }
    i -= NFC;
    if (i < NCV) {
        int o = i/1536, r = i%1536, dk = r>>9, ci = r&511;
        Bc1[i] = f2s(c1w[(o*512+ci)*3+dk]); return;
    }
    i -= NCV;
    if (i < NCV) {
        int o = i/1536, r = i%1536, dk = r>>9, ci = r&511;
        Bc2[i] = f2s(c2w[(o*512+ci)*3+dk]); return;
    }
    i -= NCV;
    if (i < NQ) {
        int w = i >> 12, rest = i & 4095;
        const float* W = (w==0)?Wq:(w==1)?Wk:Wv;
        Bqkv[i] = f2s(W[((rest>>6)&63)*64 + (rest&63)]);
    }
}

// ---------------------------------------------------------------------------
// K1: QKV projection, MFMA.
// ---------------------------------------------------------------------------
__global__ __launch_bounds__(256) void qkv_mfma(
    const float* __restrict__ x, const short* __restrict__ Bqkv,
    short* __restrict__ qf, short* __restrict__ kf, short* __restrict__ vf)
{
    __shared__ short Xs[64*72];
    __shared__ short Ws[192*72];
    const int tid = threadIdx.x;
    const int m0 = blockIdx.x * 64;
    const int h = blockIdx.y;
    const int wave = tid >> 6, lane = tid & 63;
    const int lr = lane & 15, lq = lane >> 4;

    for (int i = tid; i < 1024; i += 256) {
        int r = i >> 4, cg = (i & 15)*4;
        float4 v = *(const float4*)(x + (size_t)(m0+r)*CC + h*64 + cg);
        Xs[r*72+cg+0] = f2s(v.x); Xs[r*72+cg+1] = f2s(v.y);
        Xs[r*72+cg+2] = f2s(v.z); Xs[r*72+cg+3] = f2s(v.w);
    }
    for (int i = tid; i < 3072; i += 256) {
        int r = i >> 4, cg = (i & 15)*4;
        *(short4*)(Ws + r*72 + cg) = *(const short4*)(Bqkv + (size_t)r*64 + cg);
    }
    __syncthreads();

    f32x4 acc[12];
    #pragma unroll
    for (int nt = 0; nt < 12; ++nt) acc[nt] = {0.f,0.f,0.f,0.f};
    #pragma unroll
    for (int ks = 0; ks < 2; ++ks) {
        int ko = ks*32 + lq*8;
        short8 a = *(const short8*)(Xs + (wave*16 + lr)*72 + ko);
        #pragma unroll
        for (int nt = 0; nt < 12; ++nt) {
            short8 b = *(const short8*)(Ws + (nt*16 + lr)*72 + ko);
            acc[nt] = MFMA16(a, b, acc[nt]);
        }
    }
    #pragma unroll
    for (int nt = 0; nt < 12; ++nt) {
        int ep = nt*16 + lr;
        int w = ep >> 6, e = ep & 63;
        #pragma unroll
        for (int reg = 0; reg < 4; ++reg) {
            int m = m0 + wave*16 + lq*4 + reg;
            int n = m >> 10, s = m & 1023;
            short v = f2s(acc[nt][reg]);
            if (w == 0)      qf[(((size_t)(n*HH+h))*SS + s)*DD + e] = v;
            else if (w == 1) kf[(((size_t)(n*HH+h))*KT + s)*DD + e] = v;
            else             vf[(((size_t)(n*HH+h))*KT + s)*DD + e] = v;
        }
    }
}

// ---------------------------------------------------------------------------
// K1b: persistent tokens -> kf/vf tail.
// ---------------------------------------------------------------------------
__global__ __launch_bounds__(256) void persist_kernel(
    const float* __restrict__ pk, const float* __restrict__ pv,
    short* __restrict__ kf, short* __restrict__ vf)
{
    int idx = blockIdx.x*256 + threadIdx.x;
    if (idx >= BN*HH*PP*DD) return;
    int d = idx & 63, p = (idx >> 6) & 15, h = (idx >> 10) & 7, n = idx >> 13;
    size_t dst = (((size_t)(n*HH+h))*KT + SS + p)*DD + d;
    size_t src = ((size_t)p*HH + h)*DD + d;
    kf[dst] = f2s(pk[src]);
    vf[dst] = f2s(pv[src]);
}

// ---------------------------------------------------------------------------
// K1c: global V transpose: vt[nh][d][k] = vf[nh][k][d].
// ---------------------------------------------------------------------------
__global__ __launch_bounds__(256) void vtrans_kernel(
    const short* __restrict__ vf, short* __restrict__ vt)
{
    __shared__ short Ts[64*65];
    const int tid = threadIdx.x;
    const int k0 = blockIdx.x * 64;
    const int nh = blockIdx.y;
    for (int i = tid; i < 1024; i += 256) {
        int kk = i >> 4, dg = (i & 15)*4;
        int k = k0 + kk;
        short4 v = {0,0,0,0};
        if (k < KT) v = *(const short4*)(vf + ((size_t)nh*KT + k)*DD + dg);
        Ts[(dg+0)*65 + kk] = v.x;
        Ts[(dg+1)*65 + kk] = v.y;
        Ts[(dg+2)*65 + kk] = v.z;
        Ts[(dg+3)*65 + kk] = v.w;
    }
    __syncthreads();
    for (int i = tid; i < 1024; i += 256) {
        int d = i >> 4, kg = (i & 15)*4;
        int k = k0 + kg;
        if (k < KT) {
            short4 o;
            o.x = Ts[d*65 + kg+0]; o.y = Ts[d*65 + kg+1];
            o.z = Ts[d*65 + kg+2]; o.w = Ts[d*65 + kg+3];
            *(short4*)(vt + ((size_t)nh*DD + d)*KT + k) = o;
        }
    }
}

// ---------------------------------------------------------------------------
// K2: energy, MFMA NT. grid (17, S/64, BN*HH). E[(n,q),h,k].
// ---------------------------------------------------------------------------
__global__ __launch_bounds__(256) void energy_mfma(
    const short* __restrict__ qf, const short* __restrict__ kf,
    short* __restrict__ E)
{
    __shared__ short Qs[64*72];
    __shared__ short Ks[64*72];
    const int tid = threadIdx.x;
    const int kt = blockIdx.x;
    const int mt = blockIdx.y;
    const int nh = blockIdx.z;
    const int wave = tid >> 6, lane = tid & 63;
    const int lr = lane & 15, lq = lane >> 4;

    for (int i = tid; i < 1024; i += 256) {
        int r = i >> 4, cg = (i & 15)*4;
        *(short4*)(Qs + r*72 + cg) =
            *(const short4*)(qf + ((size_t)nh*SS + mt*64 + r)*DD + cg);
        int kcol = kt*64 + r;
        short4 kv = {0,0,0,0};
        if (kcol < KT) kv = *(const short4*)(kf + ((size_t)nh*KT + kcol)*DD + cg);
        *(short4*)(Ks + r*72 + cg) = kv;
    }
    __syncthreads();

    f32x4 acc[4];
    #pragma unroll
    for (int nt = 0; nt < 4; ++nt) acc[nt] = {0.f,0.f,0.f,0.f};
    #pragma unroll
    for (int ks = 0; ks < 2; ++ks) {
        int ko = ks*32 + lq*8;
        short8 a = *(const short8*)(Qs + (wave*16 + lr)*72 + ko);
        #pragma unroll
        for (int nt = 0; nt < 4; ++nt) {
            short8 b = *(const short8*)(Ks + (nt*16 + lr)*72 + ko);
            acc[nt] = MFMA16(a, b, acc[nt]);
        }
    }
    const int n = nh >> 3, h = nh & 7;
    #pragma unroll
    for (int nt = 0; nt < 4; ++nt) {
        int kcol = kt*64 + nt*16 + lr;
        if (kcol >= KT) continue;
        #pragma unroll
        for (int reg = 0; reg < 4; ++reg) {
            int q = mt*64 + wave*16 + lq*4 + reg;
            E[(((size_t)(n*SS + q))*HH + h)*KT + kcol] = f2s(acc[nt][reg]);
        }
    }
}

// ---------------------------------------------------------------------------
// K3: softmax, no-max (premixed |t| bounded -> f32-safe; shift-invariant).
// 512 threads/block; thread owns ADJACENT pair k = 2*tid, 2*tid+1 -> all E
// traffic is coalesced short2. Persistent cols are a tid<16 tail. LDS ~0.8 KB.
// ---------------------------------------------------------------------------
__global__ __launch_bounds__(512) void softmax_kernel(
    short* __restrict__ E, const int* __restrict__ mask,
    const float* __restrict__ th_pre, const float* __restrict__ th_post)
{
    __shared__ float thp[64], thq[64];
    __shared__ float wred[8][8];
    const int tid = threadIdx.x;
    const int wave = tid >> 6, lane = tid & 63;
    const int blk = blockIdx.x;              // n*SS + q
    const int n = blk >> 10, q = blk & 1023;
    if (tid < 64) { thp[tid] = th_pre[tid]; thq[tid] = th_post[tid]; }
    __syncthreads();
    short* Eb = E + (size_t)blk*HH*KT;

    const float sl[8] = {0.5f,0.25f,0.125f,0.0625f,
                         0.03125f,0.015625f,0.0078125f,0.00390625f};
    const float invs = 0.044194173824159216f;   // 1/sqrt(512)
    const int* mrow = mask + (size_t)n*SS*SS + (size_t)q*SS;

    const int k0 = tid*2;                    // 0..1022, pair (k0, k0+1)
    const int2 mk = *(const int2*)(mrow + k0);
    const f32x2 dist = { fabsf((float)(q - k0)), fabsf((float)(q - k0 - 1)) };

    f32x2 tp[8];
    float tl[8];
    float sm[8];
    #pragma unroll
    for (int g = 0; g < 8; ++g) { sm[g] = 0.f; tl[g] = 0.f; }

    {
        f32x2 a[8];
        #pragma unroll
        for (int g = 0; g < 8; ++g) {
            short2 s = *(const short2*)(Eb + g*KT + k0);
            a[g].x = s2f(s.x) - dist.x*sl[g];
            a[g].y = s2f(s.y) - dist.y*sl[g];
        }
        #pragma unroll
        for (int h = 0; h < 8; ++h) {
            f32x2 t = {0.f, 0.f};
            #pragma unroll
            for (int g = 0; g < 8; ++g) {
                float c = thp[h*8 + g];
                t.x = fmaf(c, a[g].x, t.x);
                t.y = fmaf(c, a[g].y, t.y);
            }
            if (mk.x == 0) t.x = -1e4f;
            if (mk.y == 0) t.y = -1e4f;
            f32x2 e;
            e.x = __expf(t.x * invs);
            e.y = __expf(t.y * invs);
            tp[h] = e;
            sm[h] += e.x + e.y;
        }
    }
    // tail: persistent keys (no ALiBi, mask padded 1)
    if (tid < 16) {
        const int k = 1024 + tid;
        float a[8];
        #pragma unroll
        for (int g = 0; g < 8; ++g) a[g] = s2f(Eb[g*KT + k]);
        #pragma unroll
        for (int h = 0; h < 8; ++h) {
            float t = 0.f;
            #pragma unroll
            for (int g = 0; g < 8; ++g) t = fmaf(thp[h*8 + g], a[g], t);
            float e = __expf(t * invs);
            tl[h] = e;
            sm[h] += e;
        }
    }
    // sum reduce: wave shuffle + cross-wave (8 waves) combine
    #pragma unroll
    for (int g = 0; g < 8; ++g) {
        #pragma unroll
        for (int off = 32; off > 0; off >>= 1)
            sm[g] += __shfl_xor(sm[g], off);
    }
    if (lane == 0) {
        #pragma unroll
        for (int g = 0; g < 8; ++g) wred[wave][g] = sm[g];
    }
    __syncthreads();
    float lred[8];
    #pragma unroll
    for (int g = 0; g < 8; ++g) {
        float s = 0.f;
        #pragma unroll
        for (int w = 0; w < 8; ++w) s += wred[w][g];
        lred[g] = 1.0f / s;
    }

    // postmix (1/l folded) + coalesced short2 stores
    {
        f32x2 e[8];
        #pragma unroll
        for (int g = 0; g < 8; ++g) {
            e[g].x = tp[g].x * lred[g];
            e[g].y = tp[g].y * lred[g];
        }
        #pragma unroll
        for (int h = 0; h < 8; ++h) {
            f32x2 t = {0.f, 0.f};
            #pragma unroll
            for (int g = 0; g < 8; ++g) {
                float c = thq[h*8 + g];
                t.x = fmaf(c, e[g].x, t.x);
                t.y = fmaf(c, e[g].y, t.y);
            }
            short2 o;
            o.x = f2s(t.x);
            o.y = f2s(t.y);
            *(short2*)(Eb + h*KT + k0) = o;
        }
    }
    if (tid < 16) {
        const int k = 1024 + tid;
        float e[8];
        #pragma unroll
        for (int g = 0; g < 8; ++g) e[g] = tl[g] * lred[g];
        #pragma unroll
        for (int h = 0; h < 8; ++h) {
            float t = 0.f;
            #pragma unroll
            for (int g = 0; g < 8; ++g) t = fmaf(thq[h*8 + g], e[g], t);
            Eb[h*KT + k] = f2s(t);
        }
    }
}

// ---------------------------------------------------------------------------
// K4: PV via vt, NT-GEMM, q-tile 32, register-prefetch dbuf. grid (32, 64).
// ---------------------------------------------------------------------------
__device__ __forceinline__ void pv_loadP(const short* __restrict__ E,
    int n, int h, int ql0, int kt, int tid, short4* rp)
{
    #pragma unroll
    for (int j = 0; j < 2; ++j) {
        int i = tid + j*256;
        int r = i >> 4, cg = (i & 15)*4;
        int k = kt*64 + cg;
        short4 v = {0,0,0,0};
        if (k < KT)
            v = *(const short4*)(E + (((size_t)(n*SS + ql0 + r))*HH + h)*KT + k);
        rp[j] = v;
    }
}
__device__ __forceinline__ void pv_loadV(const short* __restrict__ vt,
    int nh, int kt, int tid, short4* rv)
{
    #pragma unroll
    for (int j = 0; j < 4; ++j) {
        int i = tid + j*256;
        int r = i >> 4, cg = (i & 15)*4;
        int k = kt*64 + cg;
        short4 v = {0,0,0,0};
        if (k < KT)
            v = *(const short4*)(vt + ((size_t)nh*DD + r)*KT + k);
        rv[j] = v;
    }
}

__global__ __launch_bounds__(256) void pv_mfma(
    const short* __restrict__ E, const short* __restrict__ vt,
    short* __restrict__ AO)
{
    __shared__ short Ps[32*72];
    __shared__ short Vs[64*72];
    const int tid = threadIdx.x;
    const int ql0 = blockIdx.x * 32;
    const int nh = blockIdx.y;
    const int n = nh >> 3, h = nh & 7;
    const int wave = tid >> 6, lane = tid & 63;
    const int lr = lane & 15, lq = lane >> 4;
    const int mh = wave & 1, nb = (wave >> 1)*32;

    short4 rp[2], rv[4];
    pv_loadP(E, n, h, ql0, 0, tid, rp);
    pv_loadV(vt, nh, 0, tid, rv);

    f32x4 acc[2];
    acc[0] = {0.f,0.f,0.f,0.f}; acc[1] = {0.f,0.f,0.f,0.f};

    for (int kt = 0; kt < 17; ++kt) {
        if (kt) __syncthreads();
        #pragma unroll
        for (int j = 0; j < 2; ++j) {
            int i = tid + j*256;
            *(short4*)(Ps + (i >> 4)*72 + (i & 15)*4) = rp[j];
        }
        #pragma unroll
        for (int j = 0; j < 4; ++j) {
            int i = tid + j*256;
            *(short4*)(Vs + (i >> 4)*72 + (i & 15)*4) = rv[j];
        }
        __syncthreads();
        if (kt + 1 < 17) {
            pv_loadP(E, n, h, ql0, kt+1, tid, rp);
            pv_loadV(vt, nh, kt+1, tid, rv);
        }
        #pragma unroll
        for (int ks = 0; ks < 2; ++ks) {
            int ko = ks*32 + lq*8;
            short8 a = *(const short8*)(Ps + (mh*16 + lr)*72 + ko);
            #pragma unroll
            for (int nt = 0; nt < 2; ++nt) {
                short8 b = *(const short8*)(Vs + (nb + nt*16 + lr)*72 + ko);
                acc[nt] = MFMA16(a, b, acc[nt]);
            }
        }
    }
    #pragma unroll
    for (int nt = 0; nt < 2; ++nt) {
        int d = nb + nt*16 + lr;
        #pragma unroll
        for (int reg = 0; reg < 4; ++reg) {
            int qg = ql0 + mh*16 + lq*4 + reg;
            AO[((size_t)(n*SS) + qg)*CC + h*64 + d] = f2s(acc[nt][reg]);
        }
    }
}

// ---------------------------------------------------------------------------
// K5: fc, 64x64 tile, XCD-swizzled, register-prefetch dbuf. K=512.
// ---------------------------------------------------------------------------
__device__ __forceinline__ void g_load4(const short* __restrict__ src,
    size_t rowstride, int row0, int col0, int tid, short4* r)
{
    #pragma unroll
    for (int j = 0; j < 4; ++j) {
        int i = tid + j*256;
        int rr = i >> 4, cg = (i & 15)*4;
        r[j] = *(const short4*)(src + (size_t)(row0 + rr)*rowstride + col0 + cg);
    }
}
__device__ __forceinline__ void lds_store4(short* __restrict__ dst,
    int tid, const short4* r)
{
    #pragma unroll
    for (int j = 0; j < 4; ++j) {
        int i = tid + j*256;
        *(short4*)(dst + (i >> 4)*72 + (i & 15)*4) = r[j];
    }
}

__global__ __launch_bounds__(256) void fc_mfma(
    const short* __restrict__ A, const short* __restrict__ Bt,
    const float* __restrict__ bias, const float* __restrict__ x,
    short* __restrict__ out)
{
    __shared__ short As[64*72];
    __shared__ short Bs[64*72];
    const int tid = threadIdx.x;
    const int lin = blockIdx.x + 8*blockIdx.y;      // grid (8,128)
    const int xcd = lin & 7, slot = lin >> 3;
    const int m0 = (xcd*16 + (slot & 15))*64;
    const int n0 = (slot >> 4)*64;
    const int wave = tid >> 6, lane = tid & 63;
    const int lr = lane & 15, lq = lane >> 4;

    short4 ra[4], rb[4];
    g_load4(A, CC, m0, 0, tid, ra);
    g_load4(Bt, CC, n0, 0, tid, rb);

    f32x4 acc[4];
    #pragma unroll
    for (int nt = 0; nt < 4; ++nt) acc[nt] = {0.f,0.f,0.f,0.f};

    for (int kt = 0; kt < CC; kt += 64) {
        if (kt) __syncthreads();
        lds_store4(As, tid, ra);
        lds_store4(Bs, tid, rb);
        __syncthreads();
        if (kt + 64 < CC) {
            g_load4(A, CC, m0, kt+64, tid, ra);
            g_load4(Bt, CC, n0, kt+64, tid, rb);
        }
        #pragma unroll
        for (int ks = 0; ks < 2; ++ks) {
            int ko = ks*32 + lq*8;
            short8 a = *(const short8*)(As + (wave*16 + lr)*72 + ko);
            #pragma unroll
            for (int nt = 0; nt < 4; ++nt) {
                short8 b = *(const short8*)(Bs + (nt*16 + lr)*72 + ko);
                acc[nt] = MFMA16(a, b, acc[nt]);
            }
        }
    }
    #pragma unroll
    for (int nt = 0; nt < 4; ++nt) {
        int nn = n0 + nt*16 + lr;
        #pragma unroll
        for (int reg = 0; reg < 4; ++reg) {
            int m = m0 + wave*16 + lq*4 + reg;
            out[(size_t)m*CC + nn] =
                f2s(acc[nt][reg] + bias[nn] + x[(size_t)m*CC + nn]);
        }
    }
}

// ---------------------------------------------------------------------------
// K6: causal conv as NT GEMM K=1536, 64x64, XCD-swizzled, prefetch dbuf.
// ---------------------------------------------------------------------------
__device__ __forceinline__ void conv_loadA(const short* __restrict__ A,
    int m0, int kt, int tid, short4* ra)
{
    const int shift = (kt >> 9) - 2;
    const int ci0 = kt & 511;
    #pragma unroll
    for (int j = 0; j < 4; ++j) {
        int i = tid + j*256;
        int rr = i >> 4, cg = (i & 15)*4;
        int m = m0 + rr;
        int s = m & (SS-1);
        short4 v = {0,0,0,0};
        if (s + shift >= 0)
            v = *(const short4*)(A + (size_t)(m + shift)*CC + ci0 + cg);
        ra[j] = v;
    }
}

__global__ __launch_bounds__(256) void conv_mfma(
    const short* __restrict__ A, const short* __restrict__ Bt,
    const float* __restrict__ bias, short* __restrict__ out)
{
    __shared__ short As[64*72];
    __shared__ short Bs[64*72];
    const int tid = threadIdx.x;
    const int lin = blockIdx.x + 8*blockIdx.y;      // grid (8,128)
    const int xcd = lin & 7, slot = lin >> 3;
    const int m0 = (xcd*16 + (slot & 15))*64;
    const int n0 = (slot >> 4)*64;
    const int wave = tid >> 6, lane = tid & 63;
    const int lr = lane & 15, lq = lane >> 4;

    short4 ra[4], rb[4];
    conv_loadA(A, m0, 0, tid, ra);
    g_load4(Bt, 1536, n0, 0, tid, rb);

    f32x4 acc[4];
    #pragma unroll
    for (int nt = 0; nt < 4; ++nt) acc[nt] = {0.f,0.f,0.f,0.f};

    for (int kt = 0; kt < 1536; kt += 64) {
        if (kt) __syncthreads();
        lds_store4(As, tid, ra);
        lds_store4(Bs, tid, rb);
        __syncthreads();
        if (kt + 64 < 1536) {
            conv_loadA(A, m0, kt+64, tid, ra);
            g_load4(Bt, 1536, n0, kt+64, tid, rb);
        }
        #pragma unroll
        for (int ks = 0; ks < 2; ++ks) {
            int ko = ks*32 + lq*8;
            short8 a = *(const short8*)(As + (wave*16 + lr)*72 + ko);
            #pragma unroll
            for (int nt = 0; nt < 4; ++nt) {
                short8 b = *(const short8*)(Bs + (nt*16 + lr)*72 + ko);
                acc[nt] = MFMA16(a, b, acc[nt]);
            }
        }
    }
    #pragma unroll
    for (int nt = 0; nt < 4; ++nt) {
        int nn = n0 + nt*16 + lr;
        #pragma unroll
        for (int reg = 0; reg < 4; ++reg) {
            int m = m0 + wave*16 + lq*4 + reg;
            float v = acc[nt][reg] + bias[nn];
            out[(size_t)m*CC + nn] = f2s(fmaxf(v, 0.f));
        }
    }
}

// ---------------------------------------------------------------------------
// K7: out = LN(relu(c2 + xres) masked) * g + b.  short2 in / float2 out.
// ---------------------------------------------------------------------------
__global__ __launch_bounds__(256) void final_kernel(
    const short* __restrict__ c2, const short* __restrict__ xres,
    const int* __restrict__ mask, const float* __restrict__ g,
    const float* __restrict__ b, float* __restrict__ out)
{
    __shared__ float red[256];
    const int tid = threadIdx.x;
    const int m = blockIdx.x;
    const int n = m >> 10, s = m & 1023;
    const int mk = mask[(size_t)n*SS*SS + (size_t)s*SS];
    const int c0 = tid*2;

    short2 ca = *(const short2*)(c2 + (size_t)m*CC + c0);
    short2 xa = *(const short2*)(xres + (size_t)m*CC + c0);
    float v0 = fmaxf(s2f(ca.x) + s2f(xa.x), 0.f);
    float v1 = fmaxf(s2f(ca.y) + s2f(xa.y), 0.f);
    if (mk == 0) { v0 = 0.f; v1 = 0.f; }

    red[tid] = v0 + v1;
    __syncthreads();
    for (int off = 128; off > 0; off >>= 1) {
        if (tid < off) red[tid] += red[tid + off];
        __syncthreads();
    }
    float mu = red[0] * (1.0f/512.0f);
    __syncthreads();
    float d0 = v0 - mu, d1 = v1 - mu;
    red[tid] = d0*d0 + d1*d1;
    __syncthreads();
    for (int off = 128; off > 0; off >>= 1) {
        if (tid < off) red[tid] += red[tid + off];
        __syncthreads();
    }
    float rstd = rsqrtf(red[0] * (1.0f/512.0f) + 1e-5f);
    float2 gg = *(const float2*)(g + c0);
    float2 bb = *(const float2*)(b + c0);
    float2 o;
    o.x = d0*rstd*gg.x + bb.x;
    o.y = d1*rstd*gg.y + bb.y;
    *(float2*)(out + (size_t)m*CC + c0) = o;
}

// ---------------------------------------------------------------------------
extern "C" void kernel_launch(void* const* d_in, const int* in_sizes, int n_in,
                              void* d_out, int out_size, void* d_ws, size_t ws_size,
                              hipStream_t stream)
{
    const float* x      = (const float*)d_in[0];
    const int*   mask   = (const int*)  d_in[1];
    const float* Wq     = (const float*)d_in[2];
    const float* Wk     = (const float*)d_in[3];
    const float* Wv     = (const float*)d_in[4];
    const float* pk     = (const float*)d_in[5];
    const float* pv     = (const float*)d_in[6];
    const float* th_pre = (const float*)d_in[7];
    const float* th_post= (const float*)d_in[8];
    const float* fc_w   = (const float*)d_in[9];
    const float* fc_b   = (const float*)d_in[10];
    const float* c1w    = (const float*)d_in[11];
    const float* c1b    = (const float*)d_in[12];
    const float* c2w    = (const float*)d_in[13];
    const float* c2b    = (const float*)d_in[14];
    const float* lng    = (const float*)d_in[15];
    const float* lnb    = (const float*)d_in[16];
    float* out = (float*)d_out;
    (void)in_sizes; (void)n_in; (void)out_size; (void)ws_size;

    char* ws = (char*)d_ws;
    const size_t SZ_Q  = (size_t)BN*HH*SS*DD*2;    //  8.39 MB
    const size_t SZ_K  = (size_t)BN*HH*KT*DD*2;    //  8.52 MB
    const size_t SZ_VT = (size_t)BN*HH*DD*KT*2;    //  8.52 MB
    const size_t SZ_E  = (size_t)BN*SS*HH*KT*2;    // 136.3 MB
    const size_t SZ_A  = (size_t)BN*SS*CC*2;       //  8.39 MB

    short* qf  = (short*)(ws);
    short* kf  = (short*)(ws + SZ_Q);
    short* vf  = (short*)(ws + SZ_Q + SZ_K);
    short* vt  = (short*)(ws + SZ_Q + 2*SZ_K);
    short* E   = (short*)(ws + SZ_Q + 2*SZ_K + SZ_VT);
    short* AO  = (short*)(ws + SZ_Q + 2*SZ_K + SZ_VT + SZ_E);
    char*  wend = ws + SZ_Q + 2*SZ_K + SZ_VT + SZ_E + SZ_A;
    short* Bfc = (short*)(wend);
    short* Bc1 = (short*)(wend + 512*512*2);
    short* Bc2 = (short*)(wend + 512*512*2 + 512*1536*2);
    short* Bqkv= (short*)(wend + 512*512*2 + 2*512*1536*2);
    short* xres = qf;
    short* h1   = kf;
    short* c2   = vf;
    // total ws ~= 182.2 MB

    {
        int total = 512*512 + 2*512*1536 + 3*64*64;
        prep_kernel<<<(total + 255)/256, 256, 0, stream>>>(
            fc_w, c1w, c2w, Wq, Wk, Wv, Bfc, Bc1, Bc2, Bqkv);
    }
    qkv_mfma<<<dim3(BN*SS/64, HH), 256, 0, stream>>>(x, Bqkv, qf, kf, vf);
    persist_kernel<<<(BN*HH*PP*DD + 255)/256, 256, 0, stream>>>(pk, pv, kf, vf);
    vtrans_kernel<<<dim3(17, BN*HH), 256, 0, stream>>>(vf, vt);

    energy_mfma<<<dim3(17, SS/64, BN*HH), 256, 0, stream>>>(qf, kf, E);
    softmax_kernel<<<BN*SS, 512, 0, stream>>>(E, mask, th_pre, th_post);
    pv_mfma<<<dim3(SS/32, BN*HH), 256, 0, stream>>>(E, vt, AO);

    fc_mfma<<<dim3(8, 128), 256, 0, stream>>>(AO, Bfc, fc_b, x, xres);
    conv_mfma<<<dim3(8, 128), 256, 0, stream>>>(xres, Bc1, c1b, h1);
    conv_mfma<<<dim3(8, 128), 256, 0, stream>>>(h1, Bc2, c2b, c2);
    final_kernel<<<BN*SS, 256, 0, stream>>>(c2, xres, mask, lng, lnb, out);
}

// Round 10
// 398.076 us; speedup vs baseline: 1.0084x; 1.0084x over previous
//
#include <hip/hip_runtime.h>
#include <hip/hip_bf16.h>

#define BN 8
#define SS 1024
#define CC 512
#define HH 8
#define DD 64
#define PP 16
#define KT 1040

typedef __hip_bfloat16 bf16;
typedef __attribute__((ext_vector_type(8))) short short8;
typedef __attribute__((ext_vector_type(4))) float f32x4;
typedef __attribute__((ext_vector_type(2))) float f32x2;

__device__ __forceinline__ short f2s(float v){ bf16 b = __float2bfloat16(v); return *(short*)&b; }
__device__ __forceinline__ float s2f(short s){ bf16 b; *(short*)&b = s; return __bfloat162float(b); }

#define MFMA16(a,b,c) __builtin_amdgcn_mfma_f32_16x16x32_bf16(a,b,c,0,0,0)

// ---------------------------------------------------------------------------
// P0: weight pre-conversion to bf16 NT layouts.
// ---------------------------------------------------------------------------
__global__ __launch_bounds__(256) void prep_kernel(
    const float* __restrict__ fc_w, const float* __restrict__ c1w,
    const float* __restrict__ c2w, const float* __restrict__ Wq,
    const float* __restrict__ Wk, const float* __restrict__ Wv,
    short* __restrict__ Bfc, short* __restrict__ Bc1,
    short* __restrict__ Bc2, short* __restrict__ Bqkv)
{
    int i = blockIdx.x*256 + threadIdx.x;
    const int NFC = 512*512, NCV = 512*1536, NQ = 3*64*64;
    if (i < NFC) { Bfc[i] = f2s(fc_w[i]); return; }
    i -= NFC;
    if (i < NCV) {
        int o = i/1536, r = i%1536, dk = r>>9, ci = r&511;
        Bc1[i] = f2s(c1w[(o*512+ci)*3+dk]); return;
    }
    i -= NCV;
    if (i < NCV) {
        int o = i/1536, r = i%1536, dk = r>>9, ci = r&511;
        Bc2[i] = f2s(c2w[(o*512+ci)*3+dk]); return;
    }
    i -= NCV;
    if (i < NQ) {
        int w = i >> 12, rest = i & 4095;
        const float* W = (w==0)?Wq:(w==1)?Wk:Wv;
        Bqkv[i] = f2s(W[((rest>>6)&63)*64 + (rest&63)]);
    }
}

// ---------------------------------------------------------------------------
// K1: QKV projection, MFMA.
// ---------------------------------------------------------------------------
__global__ __launch_bounds__(256) void qkv_mfma(
    const float* __restrict__ x, const short* __restrict__ Bqkv,
    short* __restrict__ qf, short* __restrict__ kf, short* __restrict__ vf)
{
    __shared__ short Xs[64*72];
    __shared__ short Ws[192*72];
    const int tid = threadIdx.x;
    const int m0 = blockIdx.x * 64;
    const int h = blockIdx.y;
    const int wave = tid >> 6, lane = tid & 63;
    const int lr = lane & 15, lq = lane >> 4;

    for (int i = tid; i < 1024; i += 256) {
        int r = i >> 4, cg = (i & 15)*4;
        float4 v = *(const float4*)(x + (size_t)(m0+r)*CC + h*64 + cg);
        Xs[r*72+cg+0] = f2s(v.x); Xs[r*72+cg+1] = f2s(v.y);
        Xs[r*72+cg+2] = f2s(v.z); Xs[r*72+cg+3] = f2s(v.w);
    }
    for (int i = tid; i < 3072; i += 256) {
        int r = i >> 4, cg = (i & 15)*4;
        *(short4*)(Ws + r*72 + cg) = *(const short4*)(Bqkv + (size_t)r*64 + cg);
    }
    __syncthreads();

    f32x4 acc[12];
    #pragma unroll
    for (int nt = 0; nt < 12; ++nt) acc[nt] = {0.f,0.f,0.f,0.f};
    #pragma unroll
    for (int ks = 0; ks < 2; ++ks) {
        int ko = ks*32 + lq*8;
        short8 a = *(const short8*)(Xs + (wave*16 + lr)*72 + ko);
        #pragma unroll
        for (int nt = 0; nt < 12; ++nt) {
            short8 b = *(const short8*)(Ws + (nt*16 + lr)*72 + ko);
            acc[nt] = MFMA16(a, b, acc[nt]);
        }
    }
    #pragma unroll
    for (int nt = 0; nt < 12; ++nt) {
        int ep = nt*16 + lr;
        int w = ep >> 6, e = ep & 63;
        #pragma unroll
        for (int reg = 0; reg < 4; ++reg) {
            int m = m0 + wave*16 + lq*4 + reg;
            int n = m >> 10, s = m & 1023;
            short v = f2s(acc[nt][reg]);
            if (w == 0)      qf[(((size_t)(n*HH+h))*SS + s)*DD + e] = v;
            else if (w == 1) kf[(((size_t)(n*HH+h))*KT + s)*DD + e] = v;
            else             vf[(((size_t)(n*HH+h))*KT + s)*DD + e] = v;
        }
    }
}

// ---------------------------------------------------------------------------
// K1b: persistent tokens -> kf/vf tail.
// ---------------------------------------------------------------------------
__global__ __launch_bounds__(256) void persist_kernel(
    const float* __restrict__ pk, const float* __restrict__ pv,
    short* __restrict__ kf, short* __restrict__ vf)
{
    int idx = blockIdx.x*256 + threadIdx.x;
    if (idx >= BN*HH*PP*DD) return;
    int d = idx & 63, p = (idx >> 6) & 15, h = (idx >> 10) & 7, n = idx >> 13;
    size_t dst = (((size_t)(n*HH+h))*KT + SS + p)*DD + d;
    size_t src = ((size_t)p*HH + h)*DD + d;
    kf[dst] = f2s(pk[src]);
    vf[dst] = f2s(pv[src]);
}

// ---------------------------------------------------------------------------
// K1c: global V transpose: vt[nh][d][k] = vf[nh][k][d].
// ---------------------------------------------------------------------------
__global__ __launch_bounds__(256) void vtrans_kernel(
    const short* __restrict__ vf, short* __restrict__ vt)
{
    __shared__ short Ts[64*65];
    const int tid = threadIdx.x;
    const int k0 = blockIdx.x * 64;
    const int nh = blockIdx.y;
    for (int i = tid; i < 1024; i += 256) {
        int kk = i >> 4, dg = (i & 15)*4;
        int k = k0 + kk;
        short4 v = {0,0,0,0};
        if (k < KT) v = *(const short4*)(vf + ((size_t)nh*KT + k)*DD + dg);
        Ts[(dg+0)*65 + kk] = v.x;
        Ts[(dg+1)*65 + kk] = v.y;
        Ts[(dg+2)*65 + kk] = v.z;
        Ts[(dg+3)*65 + kk] = v.w;
    }
    __syncthreads();
    for (int i = tid; i < 1024; i += 256) {
        int d = i >> 4, kg = (i & 15)*4;
        int k = k0 + kg;
        if (k < KT) {
            short4 o;
            o.x = Ts[d*65 + kg+0]; o.y = Ts[d*65 + kg+1];
            o.z = Ts[d*65 + kg+2]; o.w = Ts[d*65 + kg+3];
            *(short4*)(vt + ((size_t)nh*DD + d)*KT + k) = o;
        }
    }
}

// ---------------------------------------------------------------------------
// K2: energy, MFMA NT. grid (17, S/64, BN*HH). E[(n,q),h,k].
// ---------------------------------------------------------------------------
__global__ __launch_bounds__(256) void energy_mfma(
    const short* __restrict__ qf, const short* __restrict__ kf,
    short* __restrict__ E)
{
    __shared__ short Qs[64*72];
    __shared__ short Ks[64*72];
    const int tid = threadIdx.x;
    const int kt = blockIdx.x;
    const int mt = blockIdx.y;
    const int nh = blockIdx.z;
    const int wave = tid >> 6, lane = tid & 63;
    const int lr = lane & 15, lq = lane >> 4;

    for (int i = tid; i < 1024; i += 256) {
        int r = i >> 4, cg = (i & 15)*4;
        *(short4*)(Qs + r*72 + cg) =
            *(const short4*)(qf + ((size_t)nh*SS + mt*64 + r)*DD + cg);
        int kcol = kt*64 + r;
        short4 kv = {0,0,0,0};
        if (kcol < KT) kv = *(const short4*)(kf + ((size_t)nh*KT + kcol)*DD + cg);
        *(short4*)(Ks + r*72 + cg) = kv;
    }
    __syncthreads();

    f32x4 acc[4];
    #pragma unroll
    for (int nt = 0; nt < 4; ++nt) acc[nt] = {0.f,0.f,0.f,0.f};
    #pragma unroll
    for (int ks = 0; ks < 2; ++ks) {
        int ko = ks*32 + lq*8;
        short8 a = *(const short8*)(Qs + (wave*16 + lr)*72 + ko);
        #pragma unroll
        for (int nt = 0; nt < 4; ++nt) {
            short8 b = *(const short8*)(Ks + (nt*16 + lr)*72 + ko);
            acc[nt] = MFMA16(a, b, acc[nt]);
        }
    }
    const int n = nh >> 3, h = nh & 7;
    #pragma unroll
    for (int nt = 0; nt < 4; ++nt) {
        int kcol = kt*64 + nt*16 + lr;
        if (kcol >= KT) continue;
        #pragma unroll
        for (int reg = 0; reg < 4; ++reg) {
            int q = mt*64 + wave*16 + lq*4 + reg;
            E[(((size_t)(n*SS + q))*HH + h)*KT + kcol] = f2s(acc[nt][reg]);
        }
    }
}

// ---------------------------------------------------------------------------
// K3: softmax, no-max (premixed exponents bounded -> f32-safe).
// 256 threads; thread owns 2 ADJACENT pairs k=(tid+jj*256)*2 -> coalesced
// short2 traffic. th_pre pre-scaled by invs*log2e so exp is bare exp2f.
// Dead mask -> e=0 directly (== f32 exp(-1e4*invs)). Packed bf16 stores via
// __float22bfloat162_rn (v_cvt_pk_bf16_f32). LDS ~0.8 KB.
// ---------------------------------------------------------------------------
__global__ __launch_bounds__(256) void softmax_kernel(
    short* __restrict__ E, const int* __restrict__ mask,
    const float* __restrict__ th_pre, const float* __restrict__ th_post)
{
    __shared__ float thp[64], thq[64];
    __shared__ float wred[4][8];
    const int tid = threadIdx.x;
    const int wave = tid >> 6, lane = tid & 63;
    const int blk = blockIdx.x;              // n*SS + q
    const int n = blk >> 10, q = blk & 1023;
    const float invs = 0.044194173824159216f;   // 1/sqrt(512)
    const float l2e  = 1.4426950408889634f;
    if (tid < 64) { thp[tid] = th_pre[tid]*(invs*l2e); thq[tid] = th_post[tid]; }
    __syncthreads();
    short* Eb = E + (size_t)blk*HH*KT;

    const float sl[8] = {0.5f,0.25f,0.125f,0.0625f,
                         0.03125f,0.015625f,0.0078125f,0.00390625f};
    const int* mrow = mask + (size_t)n*SS*SS + (size_t)q*SS;

    f32x2 tp[2][8];
    float tl[8];
    float sm[8];
    #pragma unroll
    for (int g = 0; g < 8; ++g) { sm[g] = 0.f; tl[g] = 0.f; }

    #pragma unroll
    for (int jj = 0; jj < 2; ++jj) {
        const int k0 = (tid + jj*256)*2;     // 0..1022, adjacent pair
        const int2 mk = *(const int2*)(mrow + k0);
        const f32x2 dist = { fabsf((float)(q - k0)), fabsf((float)(q - k0 - 1)) };
        f32x2 a[8];
        #pragma unroll
        for (int g = 0; g < 8; ++g) {
            short2 s = *(const short2*)(Eb + g*KT + k0);
            a[g].x = s2f(s.x) - dist.x*sl[g];
            a[g].y = s2f(s.y) - dist.y*sl[g];
        }
        #pragma unroll
        for (int h = 0; h < 8; ++h) {
            f32x2 t = {0.f, 0.f};
            #pragma unroll
            for (int g = 0; g < 8; ++g) {
                float c = thp[h*8 + g];      // pre-scaled: exponent base-2
                t.x = fmaf(c, a[g].x, t.x);
                t.y = fmaf(c, a[g].y, t.y);
            }
            f32x2 e;
            e.x = (mk.x == 0) ? 0.f : exp2f(t.x);
            e.y = (mk.y == 0) ? 0.f : exp2f(t.y);
            tp[jj][h] = e;
            sm[h] += e.x + e.y;
        }
    }
    // tail: persistent keys (no ALiBi, mask padded 1)
    if (tid < 16) {
        const int k = 1024 + tid;
        float a[8];
        #pragma unroll
        for (int g = 0; g < 8; ++g) a[g] = s2f(Eb[g*KT + k]);
        #pragma unroll
        for (int h = 0; h < 8; ++h) {
            float t = 0.f;
            #pragma unroll
            for (int g = 0; g < 8; ++g) t = fmaf(thp[h*8 + g], a[g], t);
            float e = exp2f(t);
            tl[h] = e;
            sm[h] += e;
        }
    }
    // sum reduce: wave shuffle + cross-wave combine
    #pragma unroll
    for (int g = 0; g < 8; ++g) {
        #pragma unroll
        for (int off = 32; off > 0; off >>= 1)
            sm[g] += __shfl_xor(sm[g], off);
    }
    if (lane == 0) {
        #pragma unroll
        for (int g = 0; g < 8; ++g) wred[wave][g] = sm[g];
    }
    __syncthreads();
    float lred[8];
    #pragma unroll
    for (int g = 0; g < 8; ++g)
        lred[g] = 1.0f / (wred[0][g] + wred[1][g] + wred[2][g] + wred[3][g]);

    // postmix (1/l folded) + packed bf16 coalesced stores
    #pragma unroll
    for (int jj = 0; jj < 2; ++jj) {
        const int k0 = (tid + jj*256)*2;
        f32x2 e[8];
        #pragma unroll
        for (int g = 0; g < 8; ++g) {
            e[g].x = tp[jj][g].x * lred[g];
            e[g].y = tp[jj][g].y * lred[g];
        }
        #pragma unroll
        for (int h = 0; h < 8; ++h) {
            f32x2 t = {0.f, 0.f};
            #pragma unroll
            for (int g = 0; g < 8; ++g) {
                float c = thq[h*8 + g];
                t.x = fmaf(c, e[g].x, t.x);
                t.y = fmaf(c, e[g].y, t.y);
            }
            __hip_bfloat162 o2 = __float22bfloat162_rn(make_float2(t.x, t.y));
            *(__hip_bfloat162*)(Eb + h*KT + k0) = o2;
        }
    }
    if (tid < 16) {
        const int k = 1024 + tid;
        float e[8];
        #pragma unroll
        for (int g = 0; g < 8; ++g) e[g] = tl[g] * lred[g];
        #pragma unroll
        for (int h = 0; h < 8; ++h) {
            float t = 0.f;
            #pragma unroll
            for (int g = 0; g < 8; ++g) t = fmaf(thq[h*8 + g], e[g], t);
            Eb[h*KT + k] = f2s(t);
        }
    }
}

// ---------------------------------------------------------------------------
// K4: PV via vt, NT-GEMM, q-tile 32, register-prefetch dbuf. grid (32, 64).
// ---------------------------------------------------------------------------
__device__ __forceinline__ void pv_loadP(const short* __restrict__ E,
    int n, int h, int ql0, int kt, int tid, short4* rp)
{
    #pragma unroll
    for (int j = 0; j < 2; ++j) {
        int i = tid + j*256;
        int r = i >> 4, cg = (i & 15)*4;
        int k = kt*64 + cg;
        short4 v = {0,0,0,0};
        if (k < KT)
            v = *(const short4*)(E + (((size_t)(n*SS + ql0 + r))*HH + h)*KT + k);
        rp[j] = v;
    }
}
__device__ __forceinline__ void pv_loadV(const short* __restrict__ vt,
    int nh, int kt, int tid, short4* rv)
{
    #pragma unroll
    for (int j = 0; j < 4; ++j) {
        int i = tid + j*256;
        int r = i >> 4, cg = (i & 15)*4;
        int k = kt*64 + cg;
        short4 v = {0,0,0,0};
        if (k < KT)
            v = *(const short4*)(vt + ((size_t)nh*DD + r)*KT + k);
        rv[j] = v;
    }
}

__global__ __launch_bounds__(256) void pv_mfma(
    const short* __restrict__ E, const short* __restrict__ vt,
    short* __restrict__ AO)
{
    __shared__ short Ps[32*72];
    __shared__ short Vs[64*72];
    const int tid = threadIdx.x;
    const int ql0 = blockIdx.x * 32;
    const int nh = blockIdx.y;
    const int n = nh >> 3, h = nh & 7;
    const int wave = tid >> 6, lane = tid & 63;
    const int lr = lane & 15, lq = lane >> 4;
    const int mh = wave & 1, nb = (wave >> 1)*32;

    short4 rp[2], rv[4];
    pv_loadP(E, n, h, ql0, 0, tid, rp);
    pv_loadV(vt, nh, 0, tid, rv);

    f32x4 acc[2];
    acc[0] = {0.f,0.f,0.f,0.f}; acc[1] = {0.f,0.f,0.f,0.f};

    for (int kt = 0; kt < 17; ++kt) {
        if (kt) __syncthreads();
        #pragma unroll
        for (int j = 0; j < 2; ++j) {
            int i = tid + j*256;
            *(short4*)(Ps + (i >> 4)*72 + (i & 15)*4) = rp[j];
        }
        #pragma unroll
        for (int j = 0; j < 4; ++j) {
            int i = tid + j*256;
            *(short4*)(Vs + (i >> 4)*72 + (i & 15)*4) = rv[j];
        }
        __syncthreads();
        if (kt + 1 < 17) {
            pv_loadP(E, n, h, ql0, kt+1, tid, rp);
            pv_loadV(vt, nh, kt+1, tid, rv);
        }
        #pragma unroll
        for (int ks = 0; ks < 2; ++ks) {
            int ko = ks*32 + lq*8;
            short8 a = *(const short8*)(Ps + (mh*16 + lr)*72 + ko);
            #pragma unroll
            for (int nt = 0; nt < 2; ++nt) {
                short8 b = *(const short8*)(Vs + (nb + nt*16 + lr)*72 + ko);
                acc[nt] = MFMA16(a, b, acc[nt]);
            }
        }
    }
    #pragma unroll
    for (int nt = 0; nt < 2; ++nt) {
        int d = nb + nt*16 + lr;
        #pragma unroll
        for (int reg = 0; reg < 4; ++reg) {
            int qg = ql0 + mh*16 + lq*4 + reg;
            AO[((size_t)(n*SS) + qg)*CC + h*64 + d] = f2s(acc[nt][reg]);
        }
    }
}

// ---------------------------------------------------------------------------
// K5: fc, 64x64 tile, XCD-swizzled, register-prefetch dbuf. K=512.
// ---------------------------------------------------------------------------
__device__ __forceinline__ void g_load4(const short* __restrict__ src,
    size_t rowstride, int row0, int col0, int tid, short4* r)
{
    #pragma unroll
    for (int j = 0; j < 4; ++j) {
        int i = tid + j*256;
        int rr = i >> 4, cg = (i & 15)*4;
        r[j] = *(const short4*)(src + (size_t)(row0 + rr)*rowstride + col0 + cg);
    }
}
__device__ __forceinline__ void lds_store4(short* __restrict__ dst,
    int tid, const short4* r)
{
    #pragma unroll
    for (int j = 0; j < 4; ++j) {
        int i = tid + j*256;
        *(short4*)(dst + (i >> 4)*72 + (i & 15)*4) = r[j];
    }
}

__global__ __launch_bounds__(256) void fc_mfma(
    const short* __restrict__ A, const short* __restrict__ Bt,
    const float* __restrict__ bias, const float* __restrict__ x,
    short* __restrict__ out)
{
    __shared__ short As[64*72];
    __shared__ short Bs[64*72];
    const int tid = threadIdx.x;
    const int lin = blockIdx.x + 8*blockIdx.y;      // grid (8,128)
    const int xcd = lin & 7, slot = lin >> 3;
    const int m0 = (xcd*16 + (slot & 15))*64;
    const int n0 = (slot >> 4)*64;
    const int wave = tid >> 6, lane = tid & 63;
    const int lr = lane & 15, lq = lane >> 4;

    short4 ra[4], rb[4];
    g_load4(A, CC, m0, 0, tid, ra);
    g_load4(Bt, CC, n0, 0, tid, rb);

    f32x4 acc[4];
    #pragma unroll
    for (int nt = 0; nt < 4; ++nt) acc[nt] = {0.f,0.f,0.f,0.f};

    for (int kt = 0; kt < CC; kt += 64) {
        if (kt) __syncthreads();
        lds_store4(As, tid, ra);
        lds_store4(Bs, tid, rb);
        __syncthreads();
        if (kt + 64 < CC) {
            g_load4(A, CC, m0, kt+64, tid, ra);
            g_load4(Bt, CC, n0, kt+64, tid, rb);
        }
        #pragma unroll
        for (int ks = 0; ks < 2; ++ks) {
            int ko = ks*32 + lq*8;
            short8 a = *(const short8*)(As + (wave*16 + lr)*72 + ko);
            #pragma unroll
            for (int nt = 0; nt < 4; ++nt) {
                short8 b = *(const short8*)(Bs + (nt*16 + lr)*72 + ko);
                acc[nt] = MFMA16(a, b, acc[nt]);
            }
        }
    }
    #pragma unroll
    for (int nt = 0; nt < 4; ++nt) {
        int nn = n0 + nt*16 + lr;
        #pragma unroll
        for (int reg = 0; reg < 4; ++reg) {
            int m = m0 + wave*16 + lq*4 + reg;
            out[(size_t)m*CC + nn] =
                f2s(acc[nt][reg] + bias[nn] + x[(size_t)m*CC + nn]);
        }
    }
}

// ---------------------------------------------------------------------------
// K6: causal conv as NT GEMM K=1536, 64x64, XCD-swizzled, prefetch dbuf.
// ---------------------------------------------------------------------------
__device__ __forceinline__ void conv_loadA(const short* __restrict__ A,
    int m0, int kt, int tid, short4* ra)
{
    const int shift = (kt >> 9) - 2;
    const int ci0 = kt & 511;
    #pragma unroll
    for (int j = 0; j < 4; ++j) {
        int i = tid + j*256;
        int rr = i >> 4, cg = (i & 15)*4;
        int m = m0 + rr;
        int s = m & (SS-1);
        short4 v = {0,0,0,0};
        if (s + shift >= 0)
            v = *(const short4*)(A + (size_t)(m + shift)*CC + ci0 + cg);
        ra[j] = v;
    }
}

__global__ __launch_bounds__(256) void conv_mfma(
    const short* __restrict__ A, const short* __restrict__ Bt,
    const float* __restrict__ bias, short* __restrict__ out)
{
    __shared__ short As[64*72];
    __shared__ short Bs[64*72];
    const int tid = threadIdx.x;
    const int lin = blockIdx.x + 8*blockIdx.y;      // grid (8,128)
    const int xcd = lin & 7, slot = lin >> 3;
    const int m0 = (xcd*16 + (slot & 15))*64;
    const int n0 = (slot >> 4)*64;
    const int wave = tid >> 6, lane = tid & 63;
    const int lr = lane & 15, lq = lane >> 4;

    short4 ra[4], rb[4];
    conv_loadA(A, m0, 0, tid, ra);
    g_load4(Bt, 1536, n0, 0, tid, rb);

    f32x4 acc[4];
    #pragma unroll
    for (int nt = 0; nt < 4; ++nt) acc[nt] = {0.f,0.f,0.f,0.f};

    for (int kt = 0; kt < 1536; kt += 64) {
        if (kt) __syncthreads();
        lds_store4(As, tid, ra);
        lds_store4(Bs, tid, rb);
        __syncthreads();
        if (kt + 64 < 1536) {
            conv_loadA(A, m0, kt+64, tid, ra);
            g_load4(Bt, 1536, n0, kt+64, tid, rb);
        }
        #pragma unroll
        for (int ks = 0; ks < 2; ++ks) {
            int ko = ks*32 + lq*8;
            short8 a = *(const short8*)(As + (wave*16 + lr)*72 + ko);
            #pragma unroll
            for (int nt = 0; nt < 4; ++nt) {
                short8 b = *(const short8*)(Bs + (nt*16 + lr)*72 + ko);
                acc[nt] = MFMA16(a, b, acc[nt]);
            }
        }
    }
    #pragma unroll
    for (int nt = 0; nt < 4; ++nt) {
        int nn = n0 + nt*16 + lr;
        #pragma unroll
        for (int reg = 0; reg < 4; ++reg) {
            int m = m0 + wave*16 + lq*4 + reg;
            float v = acc[nt][reg] + bias[nn];
            out[(size_t)m*CC + nn] = f2s(fmaxf(v, 0.f));
        }
    }
}

// ---------------------------------------------------------------------------
// K7: out = LN(relu(c2 + xres) masked) * g + b.  short2 in / float2 out.
// ---------------------------------------------------------------------------
__global__ __launch_bounds__(256) void final_kernel(
    const short* __restrict__ c2, const short* __restrict__ xres,
    const int* __restrict__ mask, const float* __restrict__ g,
    const float* __restrict__ b, float* __restrict__ out)
{
    __shared__ float red[256];
    const int tid = threadIdx.x;
    const int m = blockIdx.x;
    const int n = m >> 10, s = m & 1023;
    const int mk = mask[(size_t)n*SS*SS + (size_t)s*SS];
    const int c0 = tid*2;

    short2 ca = *(const short2*)(c2 + (size_t)m*CC + c0);
    short2 xa = *(const short2*)(xres + (size_t)m*CC + c0);
    float v0 = fmaxf(s2f(ca.x) + s2f(xa.x), 0.f);
    float v1 = fmaxf(s2f(ca.y) + s2f(xa.y), 0.f);
    if (mk == 0) { v0 = 0.f; v1 = 0.f; }

    red[tid] = v0 + v1;
    __syncthreads();
    for (int off = 128; off > 0; off >>= 1) {
        if (tid < off) red[tid] += red[tid + off];
        __syncthreads();
    }
    float mu = red[0] * (1.0f/512.0f);
    __syncthreads();
    float d0 = v0 - mu, d1 = v1 - mu;
    red[tid] = d0*d0 + d1*d1;
    __syncthreads();
    for (int off = 128; off > 0; off >>= 1) {
        if (tid < off) red[tid] += red[tid + off];
        __syncthreads();
    }
    float rstd = rsqrtf(red[0] * (1.0f/512.0f) + 1e-5f);
    float2 gg = *(const float2*)(g + c0);
    float2 bb = *(const float2*)(b + c0);
    float2 o;
    o.x = d0*rstd*gg.x + bb.x;
    o.y = d1*rstd*gg.y + bb.y;
    *(float2*)(out + (size_t)m*CC + c0) = o;
}

// ---------------------------------------------------------------------------
extern "C" void kernel_launch(void* const* d_in, const int* in_sizes, int n_in,
                              void* d_out, int out_size, void* d_ws, size_t ws_size,
                              hipStream_t stream)
{
    const float* x      = (const float*)d_in[0];
    const int*   mask   = (const int*)  d_in[1];
    const float* Wq     = (const float*)d_in[2];
    const float* Wk     = (const float*)d_in[3];
    const float* Wv     = (const float*)d_in[4];
    const float* pk     = (const float*)d_in[5];
    const float* pv     = (const float*)d_in[6];
    const float* th_pre = (const float*)d_in[7];
    const float* th_post= (const float*)d_in[8];
    const float* fc_w   = (const float*)d_in[9];
    const float* fc_b   = (const float*)d_in[10];
    const float* c1w    = (const float*)d_in[11];
    const float* c1b    = (const float*)d_in[12];
    const float* c2w    = (const float*)d_in[13];
    const float* c2b    = (const float*)d_in[14];
    const float* lng    = (const float*)d_in[15];
    const float* lnb    = (const float*)d_in[16];
    float* out = (float*)d_out;
    (void)in_sizes; (void)n_in; (void)out_size; (void)ws_size;

    char* ws = (char*)d_ws;
    const size_t SZ_Q  = (size_t)BN*HH*SS*DD*2;    //  8.39 MB
    const size_t SZ_K  = (size_t)BN*HH*KT*DD*2;    //  8.52 MB
    const size_t SZ_VT = (size_t)BN*HH*DD*KT*2;    //  8.52 MB
    const size_t SZ_E  = (size_t)BN*SS*HH*KT*2;    // 136.3 MB
    const size_t SZ_A  = (size_t)BN*SS*CC*2;       //  8.39 MB

    short* qf  = (short*)(ws);
    short* kf  = (short*)(ws + SZ_Q);
    short* vf  = (short*)(ws + SZ_Q + SZ_K);
    short* vt  = (short*)(ws + SZ_Q + 2*SZ_K);
    short* E   = (short*)(ws + SZ_Q + 2*SZ_K + SZ_VT);
    short* AO  = (short*)(ws + SZ_Q + 2*SZ_K + SZ_VT + SZ_E);
    char*  wend = ws + SZ_Q + 2*SZ_K + SZ_VT + SZ_E + SZ_A;
    short* Bfc = (short*)(wend);
    short* Bc1 = (short*)(wend + 512*512*2);
    short* Bc2 = (short*)(wend + 512*512*2 + 512*1536*2);
    short* Bqkv= (short*)(wend + 512*512*2 + 2*512*1536*2);
    short* xres = qf;
    short* h1   = kf;
    short* c2   = vf;
    // total ws ~= 182.2 MB

    {
        int total = 512*512 + 2*512*1536 + 3*64*64;
        prep_kernel<<<(total + 255)/256, 256, 0, stream>>>(
            fc_w, c1w, c2w, Wq, Wk, Wv, Bfc, Bc1, Bc2, Bqkv);
    }
    qkv_mfma<<<dim3(BN*SS/64, HH), 256, 0, stream>>>(x, Bqkv, qf, kf, vf);
    persist_kernel<<<(BN*HH*PP*DD + 255)/256, 256, 0, stream>>>(pk, pv, kf, vf);
    vtrans_kernel<<<dim3(17, BN*HH), 256, 0, stream>>>(vf, vt);

    energy_mfma<<<dim3(17, SS/64, BN*HH), 256, 0, stream>>>(qf, kf, E);
    softmax_kernel<<<BN*SS, 256, 0, stream>>>(E, mask, th_pre, th_post);
    pv_mfma<<<dim3(SS/32, BN*HH), 256, 0, stream>>>(E, vt, AO);

    fc_mfma<<<dim3(8, 128), 256, 0, stream>>>(AO, Bfc, fc_b, x, xres);
    conv_mfma<<<dim3(8, 128), 256, 0, stream>>>(xres, Bc1, c1b, h1);
    conv_mfma<<<dim3(8, 128), 256, 0, stream>>>(h1, Bc2, c2b, c2);
    final_kernel<<<BN*SS, 256, 0, stream>>>(c2, xres, mask, lng, lnb, out);
}

// Round 11
// 367.875 us; speedup vs baseline: 1.0911x; 1.0821x over previous
//
#include <hip/hip_runtime.h>
#include <hip/hip_bf16.h>

#define BN 8
#define SS 1024
#define CC 512
#define HH 8
#define DD 64
#define PP 16
#define KT 1040

typedef __hip_bfloat16 bf16;
typedef unsigned char uchar;
typedef unsigned short ushort;
typedef __attribute__((ext_vector_type(8))) short short8;
typedef __attribute__((ext_vector_type(4))) float f32x4;
typedef __attribute__((ext_vector_type(2))) float f32x2;

__device__ __forceinline__ short f2s(float v){ bf16 b = __float2bfloat16(v); return *(short*)&b; }
__device__ __forceinline__ float s2f(short s){ bf16 b; *(short*)&b = s; return __bfloat162float(b); }
__device__ __forceinline__ uchar f2q(float v){          // f32 -> fp8 e4m3 byte
    return (uchar)__builtin_amdgcn_cvt_pk_fp8_f32(v, v, 0, false);
}

#define MFMA16(a,b,c)  __builtin_amdgcn_mfma_f32_16x16x32_bf16(a,b,c,0,0,0)
#define MFMAF8(a,b,c)  __builtin_amdgcn_mfma_f32_16x16x32_fp8_fp8(a,b,c,0,0,0)

// ---------------------------------------------------------------------------
// P0: weight pre-conversion to bf16 NT layouts.
// ---------------------------------------------------------------------------
__global__ __launch_bounds__(256) void prep_kernel(
    const float* __restrict__ fc_w, const float* __restrict__ c1w,
    const float* __restrict__ c2w, const float* __restrict__ Wq,
    const float* __restrict__ Wk, const float* __restrict__ Wv,
    short* __restrict__ Bfc, short* __restrict__ Bc1,
    short* __restrict__ Bc2, short* __restrict__ Bqkv)
{
    int i = blockIdx.x*256 + threadIdx.x;
    const int NFC = 512*512, NCV = 512*1536, NQ = 3*64*64;
    if (i < NFC) { Bfc[i] = f2s(fc_w[i]); return; }
    i -= NFC;
    if (i < NCV) {
        int o = i/1536, r = i%1536, dk = r>>9, ci = r&511;
        Bc1[i] = f2s(c1w[(o*512+ci)*3+dk]); return;
    }
    i -= NCV;
    if (i < NCV) {
        int o = i/1536, r = i%1536, dk = r>>9, ci = r&511;
        Bc2[i] = f2s(c2w[(o*512+ci)*3+dk]); return;
    }
    i -= NCV;
    if (i < NQ) {
        int w = i >> 12, rest = i & 4095;
        const float* W = (w==0)?Wq:(w==1)?Wk:Wv;
        Bqkv[i] = f2s(W[((rest>>6)&63)*64 + (rest&63)]);
    }
}

// ---------------------------------------------------------------------------
// K1: QKV projection, MFMA (bf16).
// ---------------------------------------------------------------------------
__global__ __launch_bounds__(256) void qkv_mfma(
    const float* __restrict__ x, const short* __restrict__ Bqkv,
    short* __restrict__ qf, short* __restrict__ kf, short* __restrict__ vf)
{
    __shared__ short Xs[64*72];
    __shared__ short Ws[192*72];
    const int tid = threadIdx.x;
    const int m0 = blockIdx.x * 64;
    const int h = blockIdx.y;
    const int wave = tid >> 6, lane = tid & 63;
    const int lr = lane & 15, lq = lane >> 4;

    for (int i = tid; i < 1024; i += 256) {
        int r = i >> 4, cg = (i & 15)*4;
        float4 v = *(const float4*)(x + (size_t)(m0+r)*CC + h*64 + cg);
        Xs[r*72+cg+0] = f2s(v.x); Xs[r*72+cg+1] = f2s(v.y);
        Xs[r*72+cg+2] = f2s(v.z); Xs[r*72+cg+3] = f2s(v.w);
    }
    for (int i = tid; i < 3072; i += 256) {
        int r = i >> 4, cg = (i & 15)*4;
        *(short4*)(Ws + r*72 + cg) = *(const short4*)(Bqkv + (size_t)r*64 + cg);
    }
    __syncthreads();

    f32x4 acc[12];
    #pragma unroll
    for (int nt = 0; nt < 12; ++nt) acc[nt] = {0.f,0.f,0.f,0.f};
    #pragma unroll
    for (int ks = 0; ks < 2; ++ks) {
        int ko = ks*32 + lq*8;
        short8 a = *(const short8*)(Xs + (wave*16 + lr)*72 + ko);
        #pragma unroll
        for (int nt = 0; nt < 12; ++nt) {
            short8 b = *(const short8*)(Ws + (nt*16 + lr)*72 + ko);
            acc[nt] = MFMA16(a, b, acc[nt]);
        }
    }
    #pragma unroll
    for (int nt = 0; nt < 12; ++nt) {
        int ep = nt*16 + lr;
        int w = ep >> 6, e = ep & 63;
        #pragma unroll
        for (int reg = 0; reg < 4; ++reg) {
            int m = m0 + wave*16 + lq*4 + reg;
            int n = m >> 10, s = m & 1023;
            short v = f2s(acc[nt][reg]);
            if (w == 0)      qf[(((size_t)(n*HH+h))*SS + s)*DD + e] = v;
            else if (w == 1) kf[(((size_t)(n*HH+h))*KT + s)*DD + e] = v;
            else             vf[(((size_t)(n*HH+h))*KT + s)*DD + e] = v;
        }
    }
}

// ---------------------------------------------------------------------------
// K1b: persistent tokens -> kf/vf tail (bf16).
// ---------------------------------------------------------------------------
__global__ __launch_bounds__(256) void persist_kernel(
    const float* __restrict__ pk, const float* __restrict__ pv,
    short* __restrict__ kf, short* __restrict__ vf)
{
    int idx = blockIdx.x*256 + threadIdx.x;
    if (idx >= BN*HH*PP*DD) return;
    int d = idx & 63, p = (idx >> 6) & 15, h = (idx >> 10) & 7, n = idx >> 13;
    size_t dst = (((size_t)(n*HH+h))*KT + SS + p)*DD + d;
    size_t src = ((size_t)p*HH + h)*DD + d;
    kf[dst] = f2s(pk[src]);
    vf[dst] = f2s(pv[src]);
}

// ---------------------------------------------------------------------------
// K1c: V transpose + fp8 quant: vt[nh][d][k] (fp8) = vf[nh][k][d] (bf16).
// ---------------------------------------------------------------------------
__global__ __launch_bounds__(256) void vtrans_kernel(
    const short* __restrict__ vf, uchar* __restrict__ vt)
{
    __shared__ short Ts[64*65];
    const int tid = threadIdx.x;
    const int k0 = blockIdx.x * 64;
    const int nh = blockIdx.y;
    for (int i = tid; i < 1024; i += 256) {
        int kk = i >> 4, dg = (i & 15)*4;
        int k = k0 + kk;
        short4 v = {0,0,0,0};
        if (k < KT) v = *(const short4*)(vf + ((size_t)nh*KT + k)*DD + dg);
        Ts[(dg+0)*65 + kk] = v.x;
        Ts[(dg+1)*65 + kk] = v.y;
        Ts[(dg+2)*65 + kk] = v.z;
        Ts[(dg+3)*65 + kk] = v.w;
    }
    __syncthreads();
    for (int i = tid; i < 1024; i += 256) {
        int d = i >> 4, kg = (i & 15)*4;
        int k = k0 + kg;
        if (k < KT) {
            float f0 = s2f(Ts[d*65 + kg+0]), f1 = s2f(Ts[d*65 + kg+1]);
            float f2 = s2f(Ts[d*65 + kg+2]), f3 = s2f(Ts[d*65 + kg+3]);
            int p0 = __builtin_amdgcn_cvt_pk_fp8_f32(f0, f1, 0, false);
            int p1 = __builtin_amdgcn_cvt_pk_fp8_f32(f2, f3, 0, false);
            unsigned int w = (unsigned int)(p0 & 0xffff) | ((unsigned int)p1 << 16);
            *(unsigned int*)(vt + ((size_t)nh*DD + d)*KT + k) = w;
        }
    }
}

// ---------------------------------------------------------------------------
// K2: energy, MFMA NT, fp8 raw-score output. grid (17, S/64, BN*HH).
// ---------------------------------------------------------------------------
__global__ __launch_bounds__(256) void energy_mfma(
    const short* __restrict__ qf, const short* __restrict__ kf,
    uchar* __restrict__ E)
{
    __shared__ short Qs[64*72];
    __shared__ short Ks[64*72];
    const int tid = threadIdx.x;
    const int kt = blockIdx.x;
    const int mt = blockIdx.y;
    const int nh = blockIdx.z;
    const int wave = tid >> 6, lane = tid & 63;
    const int lr = lane & 15, lq = lane >> 4;

    for (int i = tid; i < 1024; i += 256) {
        int r = i >> 4, cg = (i & 15)*4;
        *(short4*)(Qs + r*72 + cg) =
            *(const short4*)(qf + ((size_t)nh*SS + mt*64 + r)*DD + cg);
        int kcol = kt*64 + r;
        short4 kv = {0,0,0,0};
        if (kcol < KT) kv = *(const short4*)(kf + ((size_t)nh*KT + kcol)*DD + cg);
        *(short4*)(Ks + r*72 + cg) = kv;
    }
    __syncthreads();

    f32x4 acc[4];
    #pragma unroll
    for (int nt = 0; nt < 4; ++nt) acc[nt] = {0.f,0.f,0.f,0.f};
    #pragma unroll
    for (int ks = 0; ks < 2; ++ks) {
        int ko = ks*32 + lq*8;
        short8 a = *(const short8*)(Qs + (wave*16 + lr)*72 + ko);
        #pragma unroll
        for (int nt = 0; nt < 4; ++nt) {
            short8 b = *(const short8*)(Ks + (nt*16 + lr)*72 + ko);
            acc[nt] = MFMA16(a, b, acc[nt]);
        }
    }
    const int n = nh >> 3, h = nh & 7;
    #pragma unroll
    for (int nt = 0; nt < 4; ++nt) {
        int kcol = kt*64 + nt*16 + lr;
        if (kcol >= KT) continue;
        #pragma unroll
        for (int reg = 0; reg < 4; ++reg) {
            int q = mt*64 + wave*16 + lq*4 + reg;
            E[(((size_t)(n*SS + q))*HH + h)*KT + kcol] = f2q(acc[nt][reg]);
        }
    }
}

// ---------------------------------------------------------------------------
// K3: softmax, no-max (premixed exponents bounded -> f32-safe). fp8 in/out.
// 256 threads; thread owns 2 ADJACENT pairs k=(tid+jj*256)*2 -> coalesced
// ushort fp8-pair traffic. th_pre pre-scaled by invs*log2e -> bare exp2f.
// Dead mask -> e=0 directly. LDS ~0.8 KB.
// ---------------------------------------------------------------------------
__global__ __launch_bounds__(256) void softmax_kernel(
    uchar* __restrict__ E, const int* __restrict__ mask,
    const float* __restrict__ th_pre, const float* __restrict__ th_post)
{
    __shared__ float thp[64], thq[64];
    __shared__ float wred[4][8];
    const int tid = threadIdx.x;
    const int wave = tid >> 6, lane = tid & 63;
    const int blk = blockIdx.x;              // n*SS + q
    const int n = blk >> 10, q = blk & 1023;
    const float invs = 0.044194173824159216f;   // 1/sqrt(512)
    const float l2e  = 1.4426950408889634f;
    if (tid < 64) { thp[tid] = th_pre[tid]*(invs*l2e); thq[tid] = th_post[tid]; }
    __syncthreads();
    uchar* Eb = E + (size_t)blk*HH*KT;

    const float sl[8] = {0.5f,0.25f,0.125f,0.0625f,
                         0.03125f,0.015625f,0.0078125f,0.00390625f};
    const int* mrow = mask + (size_t)n*SS*SS + (size_t)q*SS;

    f32x2 tp[2][8];
    float tl[8];
    float sm[8];
    #pragma unroll
    for (int g = 0; g < 8; ++g) { sm[g] = 0.f; tl[g] = 0.f; }

    #pragma unroll
    for (int jj = 0; jj < 2; ++jj) {
        const int k0 = (tid + jj*256)*2;     // 0..1022, adjacent pair
        const int2 mk = *(const int2*)(mrow + k0);
        const f32x2 dist = { fabsf((float)(q - k0)), fabsf((float)(q - k0 - 1)) };
        f32x2 a[8];
        #pragma unroll
        for (int g = 0; g < 8; ++g) {
            ushort u = *(const ushort*)(Eb + g*KT + k0);
            f32x2 raw = __builtin_amdgcn_cvt_pk_f32_fp8((int)u, false);
            a[g].x = raw.x - dist.x*sl[g];
            a[g].y = raw.y - dist.y*sl[g];
        }
        #pragma unroll
        for (int h = 0; h < 8; ++h) {
            f32x2 t = {0.f, 0.f};
            #pragma unroll
            for (int g = 0; g < 8; ++g) {
                float c = thp[h*8 + g];      // pre-scaled: exponent base-2
                t.x = fmaf(c, a[g].x, t.x);
                t.y = fmaf(c, a[g].y, t.y);
            }
            f32x2 e;
            e.x = (mk.x == 0) ? 0.f : exp2f(t.x);
            e.y = (mk.y == 0) ? 0.f : exp2f(t.y);
            tp[jj][h] = e;
            sm[h] += e.x + e.y;
        }
    }
    // tail: persistent keys (no ALiBi, mask padded 1)
    if (tid < 16) {
        const int k = 1024 + tid;
        float a[8];
        #pragma unroll
        for (int g = 0; g < 8; ++g) {
            f32x2 r = __builtin_amdgcn_cvt_pk_f32_fp8((int)Eb[g*KT + k], false);
            a[g] = r.x;
        }
        #pragma unroll
        for (int h = 0; h < 8; ++h) {
            float t = 0.f;
            #pragma unroll
            for (int g = 0; g < 8; ++g) t = fmaf(thp[h*8 + g], a[g], t);
            float e = exp2f(t);
            tl[h] = e;
            sm[h] += e;
        }
    }
    // sum reduce: wave shuffle + cross-wave combine
    #pragma unroll
    for (int g = 0; g < 8; ++g) {
        #pragma unroll
        for (int off = 32; off > 0; off >>= 1)
            sm[g] += __shfl_xor(sm[g], off);
    }
    if (lane == 0) {
        #pragma unroll
        for (int g = 0; g < 8; ++g) wred[wave][g] = sm[g];
    }
    __syncthreads();
    float lred[8];
    #pragma unroll
    for (int g = 0; g < 8; ++g)
        lred[g] = 1.0f / (wred[0][g] + wred[1][g] + wred[2][g] + wred[3][g]);

    // postmix (1/l folded) + packed fp8 coalesced stores
    #pragma unroll
    for (int jj = 0; jj < 2; ++jj) {
        const int k0 = (tid + jj*256)*2;
        f32x2 e[8];
        #pragma unroll
        for (int g = 0; g < 8; ++g) {
            e[g].x = tp[jj][g].x * lred[g];
            e[g].y = tp[jj][g].y * lred[g];
        }
        #pragma unroll
        for (int h = 0; h < 8; ++h) {
            f32x2 t = {0.f, 0.f};
            #pragma unroll
            for (int g = 0; g < 8; ++g) {
                float c = thq[h*8 + g];
                t.x = fmaf(c, e[g].x, t.x);
                t.y = fmaf(c, e[g].y, t.y);
            }
            int p = __builtin_amdgcn_cvt_pk_fp8_f32(t.x, t.y, 0, false);
            *(ushort*)(Eb + h*KT + k0) = (ushort)p;
        }
    }
    if (tid < 16) {
        const int k = 1024 + tid;
        float e[8];
        #pragma unroll
        for (int g = 0; g < 8; ++g) e[g] = tl[g] * lred[g];
        #pragma unroll
        for (int h = 0; h < 8; ++h) {
            float t = 0.f;
            #pragma unroll
            for (int g = 0; g < 8; ++g) t = fmaf(thq[h*8 + g], e[g], t);
            Eb[h*KT + k] = f2q(t);
        }
    }
}

// ---------------------------------------------------------------------------
// K4: PV via fp8 MFMA (P' fp8 x V fp8), q-tile 32, register-prefetch dbuf.
// ---------------------------------------------------------------------------
__device__ __forceinline__ void pv_loadP(const uchar* __restrict__ E,
    int n, int h, int ql0, int kt, int tid, uint2* rp)
{
    // Ps: 32 rows x 64 fp8 = 2048 B; 256 threads x 8 B, one shot
    int r = tid >> 3, cg = (tid & 7)*8;
    int k = kt*64 + cg;
    uint2 v = {0u, 0u};
    if (k < KT)
        v = *(const uint2*)(E + (((size_t)(n*SS + ql0 + r))*HH + h)*KT + k);
    rp[0] = v;
}
__device__ __forceinline__ void pv_loadV(const uchar* __restrict__ vt,
    int nh, int kt, int tid, uint2* rv)
{
    // Vs: 64 rows x 64 fp8 = 4096 B; two shots
    #pragma unroll
    for (int j = 0; j < 2; ++j) {
        int i = tid + j*256;
        int r = i >> 3, cg = (i & 7)*8;
        int k = kt*64 + cg;
        uint2 v = {0u, 0u};
        if (k < KT)
            v = *(const uint2*)(vt + ((size_t)nh*DD + r)*KT + k);
        rv[j] = v;
    }
}

__global__ __launch_bounds__(256) void pv_mfma(
    const uchar* __restrict__ E, const uchar* __restrict__ vt,
    short* __restrict__ AO)
{
    __shared__ uchar Ps[32*72];
    __shared__ uchar Vs[64*72];
    const int tid = threadIdx.x;
    const int ql0 = blockIdx.x * 32;
    const int nh = blockIdx.y;
    const int n = nh >> 3, h = nh & 7;
    const int wave = tid >> 6, lane = tid & 63;
    const int lr = lane & 15, lq = lane >> 4;
    const int mh = wave & 1, nb = (wave >> 1)*32;

    uint2 rp[1], rv[2];
    pv_loadP(E, n, h, ql0, 0, tid, rp);
    pv_loadV(vt, nh, 0, tid, rv);

    f32x4 acc[2];
    acc[0] = {0.f,0.f,0.f,0.f}; acc[1] = {0.f,0.f,0.f,0.f};

    for (int kt = 0; kt < 17; ++kt) {
        if (kt) __syncthreads();
        {
            int r = tid >> 3, cg = (tid & 7)*8;
            *(uint2*)(Ps + r*72 + cg) = rp[0];
        }
        #pragma unroll
        for (int j = 0; j < 2; ++j) {
            int i = tid + j*256;
            *(uint2*)(Vs + (i >> 3)*72 + (i & 7)*8) = rv[j];
        }
        __syncthreads();
        if (kt + 1 < 17) {
            pv_loadP(E, n, h, ql0, kt+1, tid, rp);
            pv_loadV(vt, nh, kt+1, tid, rv);
        }
        #pragma unroll
        for (int ks = 0; ks < 2; ++ks) {
            int ko = ks*32 + lq*8;
            long a = *(const long*)(Ps + (mh*16 + lr)*72 + ko);
            #pragma unroll
            for (int nt = 0; nt < 2; ++nt) {
                long b = *(const long*)(Vs + (nb + nt*16 + lr)*72 + ko);
                acc[nt] = MFMAF8(a, b, acc[nt]);
            }
        }
    }
    #pragma unroll
    for (int nt = 0; nt < 2; ++nt) {
        int d = nb + nt*16 + lr;
        #pragma unroll
        for (int reg = 0; reg < 4; ++reg) {
            int qg = ql0 + mh*16 + lq*4 + reg;
            AO[((size_t)(n*SS) + qg)*CC + h*64 + d] = f2s(acc[nt][reg]);
        }
    }
}

// ---------------------------------------------------------------------------
// K5: fc, 64x64 tile, XCD-swizzled, register-prefetch dbuf. K=512.
// ---------------------------------------------------------------------------
__device__ __forceinline__ void g_load4(const short* __restrict__ src,
    size_t rowstride, int row0, int col0, int tid, short4* r)
{
    #pragma unroll
    for (int j = 0; j < 4; ++j) {
        int i = tid + j*256;
        int rr = i >> 4, cg = (i & 15)*4;
        r[j] = *(const short4*)(src + (size_t)(row0 + rr)*rowstride + col0 + cg);
    }
}
__device__ __forceinline__ void lds_store4(short* __restrict__ dst,
    int tid, const short4* r)
{
    #pragma unroll
    for (int j = 0; j < 4; ++j) {
        int i = tid + j*256;
        *(short4*)(dst + (i >> 4)*72 + (i & 15)*4) = r[j];
    }
}

__global__ __launch_bounds__(256) void fc_mfma(
    const short* __restrict__ A, const short* __restrict__ Bt,
    const float* __restrict__ bias, const float* __restrict__ x,
    short* __restrict__ out)
{
    __shared__ short As[64*72];
    __shared__ short Bs[64*72];
    const int tid = threadIdx.x;
    const int lin = blockIdx.x + 8*blockIdx.y;      // grid (8,128)
    const int xcd = lin & 7, slot = lin >> 3;
    const int m0 = (xcd*16 + (slot & 15))*64;
    const int n0 = (slot >> 4)*64;
    const int wave = tid >> 6, lane = tid & 63;
    const int lr = lane & 15, lq = lane >> 4;

    short4 ra[4], rb[4];
    g_load4(A, CC, m0, 0, tid, ra);
    g_load4(Bt, CC, n0, 0, tid, rb);

    f32x4 acc[4];
    #pragma unroll
    for (int nt = 0; nt < 4; ++nt) acc[nt] = {0.f,0.f,0.f,0.f};

    for (int kt = 0; kt < CC; kt += 64) {
        if (kt) __syncthreads();
        lds_store4(As, tid, ra);
        lds_store4(Bs, tid, rb);
        __syncthreads();
        if (kt + 64 < CC) {
            g_load4(A, CC, m0, kt+64, tid, ra);
            g_load4(Bt, CC, n0, kt+64, tid, rb);
        }
        #pragma unroll
        for (int ks = 0; ks < 2; ++ks) {
            int ko = ks*32 + lq*8;
            short8 a = *(const short8*)(As + (wave*16 + lr)*72 + ko);
            #pragma unroll
            for (int nt = 0; nt < 4; ++nt) {
                short8 b = *(const short8*)(Bs + (nt*16 + lr)*72 + ko);
                acc[nt] = MFMA16(a, b, acc[nt]);
            }
        }
    }
    #pragma unroll
    for (int nt = 0; nt < 4; ++nt) {
        int nn = n0 + nt*16 + lr;
        #pragma unroll
        for (int reg = 0; reg < 4; ++reg) {
            int m = m0 + wave*16 + lq*4 + reg;
            out[(size_t)m*CC + nn] =
                f2s(acc[nt][reg] + bias[nn] + x[(size_t)m*CC + nn]);
        }
    }
}

// ---------------------------------------------------------------------------
// K6: causal conv as NT GEMM K=1536, 64x64, XCD-swizzled, prefetch dbuf.
// ---------------------------------------------------------------------------
__device__ __forceinline__ void conv_loadA(const short* __restrict__ A,
    int m0, int kt, int tid, short4* ra)
{
    const int shift = (kt >> 9) - 2;
    const int ci0 = kt & 511;
    #pragma unroll
    for (int j = 0; j < 4; ++j) {
        int i = tid + j*256;
        int rr = i >> 4, cg = (i & 15)*4;
        int m = m0 + rr;
        int s = m & (SS-1);
        short4 v = {0,0,0,0};
        if (s + shift >= 0)
            v = *(const short4*)(A + (size_t)(m + shift)*CC + ci0 + cg);
        ra[j] = v;
    }
}

__global__ __launch_bounds__(256) void conv_mfma(
    const short* __restrict__ A, const short* __restrict__ Bt,
    const float* __restrict__ bias, short* __restrict__ out)
{
    __shared__ short As[64*72];
    __shared__ short Bs[64*72];
    const int tid = threadIdx.x;
    const int lin = blockIdx.x + 8*blockIdx.y;      // grid (8,128)
    const int xcd = lin & 7, slot = lin >> 3;
    const int m0 = (xcd*16 + (slot & 15))*64;
    const int n0 = (slot >> 4)*64;
    const int wave = tid >> 6, lane = tid & 63;
    const int lr = lane & 15, lq = lane >> 4;

    short4 ra[4], rb[4];
    conv_loadA(A, m0, 0, tid, ra);
    g_load4(Bt, 1536, n0, 0, tid, rb);

    f32x4 acc[4];
    #pragma unroll
    for (int nt = 0; nt < 4; ++nt) acc[nt] = {0.f,0.f,0.f,0.f};

    for (int kt = 0; kt < 1536; kt += 64) {
        if (kt) __syncthreads();
        lds_store4(As, tid, ra);
        lds_store4(Bs, tid, rb);
        __syncthreads();
        if (kt + 64 < 1536) {
            conv_loadA(A, m0, kt+64, tid, ra);
            g_load4(Bt, 1536, n0, kt+64, tid, rb);
        }
        #pragma unroll
        for (int ks = 0; ks < 2; ++ks) {
            int ko = ks*32 + lq*8;
            short8 a = *(const short8*)(As + (wave*16 + lr)*72 + ko);
            #pragma unroll
            for (int nt = 0; nt < 4; ++nt) {
                short8 b = *(const short8*)(Bs + (nt*16 + lr)*72 + ko);
                acc[nt] = MFMA16(a, b, acc[nt]);
            }
        }
    }
    #pragma unroll
    for (int nt = 0; nt < 4; ++nt) {
        int nn = n0 + nt*16 + lr;
        #pragma unroll
        for (int reg = 0; reg < 4; ++reg) {
            int m = m0 + wave*16 + lq*4 + reg;
            float v = acc[nt][reg] + bias[nn];
            out[(size_t)m*CC + nn] = f2s(fmaxf(v, 0.f));
        }
    }
}

// ---------------------------------------------------------------------------
// K7: out = LN(relu(c2 + xres) masked) * g + b.  short2 in / float2 out.
// ---------------------------------------------------------------------------
__global__ __launch_bounds__(256) void final_kernel(
    const short* __restrict__ c2, const short* __restrict__ xres,
    const int* __restrict__ mask, const float* __restrict__ g,
    const float* __restrict__ b, float* __restrict__ out)
{
    __shared__ float red[256];
    const int tid = threadIdx.x;
    const int m = blockIdx.x;
    const int n = m >> 10, s = m & 1023;
    const int mk = mask[(size_t)n*SS*SS + (size_t)s*SS];
    const int c0 = tid*2;

    short2 ca = *(const short2*)(c2 + (size_t)m*CC + c0);
    short2 xa = *(const short2*)(xres + (size_t)m*CC + c0);
    float v0 = fmaxf(s2f(ca.x) + s2f(xa.x), 0.f);
    float v1 = fmaxf(s2f(ca.y) + s2f(xa.y), 0.f);
    if (mk == 0) { v0 = 0.f; v1 = 0.f; }

    red[tid] = v0 + v1;
    __syncthreads();
    for (int off = 128; off > 0; off >>= 1) {
        if (tid < off) red[tid] += red[tid + off];
        __syncthreads();
    }
    float mu = red[0] * (1.0f/512.0f);
    __syncthreads();
    float d0 = v0 - mu, d1 = v1 - mu;
    red[tid] = d0*d0 + d1*d1;
    __syncthreads();
    for (int off = 128; off > 0; off >>= 1) {
        if (tid < off) red[tid] += red[tid + off];
        __syncthreads();
    }
    float rstd = rsqrtf(red[0] * (1.0f/512.0f) + 1e-5f);
    float2 gg = *(const float2*)(g + c0);
    float2 bb = *(const float2*)(b + c0);
    float2 o;
    o.x = d0*rstd*gg.x + bb.x;
    o.y = d1*rstd*gg.y + bb.y;
    *(float2*)(out + (size_t)m*CC + c0) = o;
}

// ---------------------------------------------------------------------------
extern "C" void kernel_launch(void* const* d_in, const int* in_sizes, int n_in,
                              void* d_out, int out_size, void* d_ws, size_t ws_size,
                              hipStream_t stream)
{
    const float* x      = (const float*)d_in[0];
    const int*   mask   = (const int*)  d_in[1];
    const float* Wq     = (const float*)d_in[2];
    const float* Wk     = (const float*)d_in[3];
    const float* Wv     = (const float*)d_in[4];
    const float* pk     = (const float*)d_in[5];
    const float* pv     = (const float*)d_in[6];
    const float* th_pre = (const float*)d_in[7];
    const float* th_post= (const float*)d_in[8];
    const float* fc_w   = (const float*)d_in[9];
    const float* fc_b   = (const float*)d_in[10];
    const float* c1w    = (const float*)d_in[11];
    const float* c1b    = (const float*)d_in[12];
    const float* c2w    = (const float*)d_in[13];
    const float* c2b    = (const float*)d_in[14];
    const float* lng    = (const float*)d_in[15];
    const float* lnb    = (const float*)d_in[16];
    float* out = (float*)d_out;
    (void)in_sizes; (void)n_in; (void)out_size; (void)ws_size;

    char* ws = (char*)d_ws;
    const size_t SZ_Q  = (size_t)BN*HH*SS*DD*2;    //  8.39 MB (bf16)
    const size_t SZ_K  = (size_t)BN*HH*KT*DD*2;    //  8.52 MB (bf16)
    const size_t SZ_VT = (size_t)BN*HH*DD*KT;      //  4.26 MB (fp8)
    const size_t SZ_E  = (size_t)BN*SS*HH*KT;      // 68.2 MB (fp8)
    const size_t SZ_A  = (size_t)BN*SS*CC*2;       //  8.39 MB (bf16)

    short* qf  = (short*)(ws);
    short* kf  = (short*)(ws + SZ_Q);
    short* vf  = (short*)(ws + SZ_Q + SZ_K);
    uchar* vt  = (uchar*)(ws + SZ_Q + 2*SZ_K);
    uchar* E   = (uchar*)(ws + SZ_Q + 2*SZ_K + SZ_VT);
    short* AO  = (short*)(ws + SZ_Q + 2*SZ_K + SZ_VT + SZ_E);
    char*  wend = ws + SZ_Q + 2*SZ_K + SZ_VT + SZ_E + SZ_A;
    short* Bfc = (short*)(wend);
    short* Bc1 = (short*)(wend + 512*512*2);
    short* Bc2 = (short*)(wend + 512*512*2 + 512*1536*2);
    short* Bqkv= (short*)(wend + 512*512*2 + 2*512*1536*2);
    short* xres = qf;    // qf dead after energy
    short* h1   = kf;    // kf dead after energy
    short* c2   = vf;    // vf dead after vtrans (pv uses vt)
    // total ws ~= 110 MB (ws_size >= 256 MiB)

    {
        int total = 512*512 + 2*512*1536 + 3*64*64;
        prep_kernel<<<(total + 255)/256, 256, 0, stream>>>(
            fc_w, c1w, c2w, Wq, Wk, Wv, Bfc, Bc1, Bc2, Bqkv);
    }
    qkv_mfma<<<dim3(BN*SS/64, HH), 256, 0, stream>>>(x, Bqkv, qf, kf, vf);
    persist_kernel<<<(BN*HH*PP*DD + 255)/256, 256, 0, stream>>>(pk, pv, kf, vf);
    vtrans_kernel<<<dim3(17, BN*HH), 256, 0, stream>>>(vf, vt);

    energy_mfma<<<dim3(17, SS/64, BN*HH), 256, 0, stream>>>(qf, kf, E);
    softmax_kernel<<<BN*SS, 256, 0, stream>>>(E, mask, th_pre, th_post);
    pv_mfma<<<dim3(SS/32, BN*HH), 256, 0, stream>>>(E, vt, AO);

    fc_mfma<<<dim3(8, 128), 256, 0, stream>>>(AO, Bfc, fc_b, x, xres);
    conv_mfma<<<dim3(8, 128), 256, 0, stream>>>(xres, Bc1, c1b, h1);
    conv_mfma<<<dim3(8, 128), 256, 0, stream>>>(h1, Bc2, c2b, c2);
    final_kernel<<<BN*SS, 256, 0, stream>>>(c2, xres, mask, lng, lnb, out);
}